// Round 2
// baseline (237.151 us; speedup 1.0000x reference)
//
#include <hip/hip_runtime.h>
#include <cstdint>

#define NB 128
#define NT 1024
#define NC 128
#define NL 128
#define NS 257
#define EPSF 1e-7f
#define CHUNK 32
#define LN2F 0.69314718055994530942f
#define NEGL2 -1.442695e30f   // *ln2 ~= -1e30 (reference NEG)

__device__ __forceinline__ float fexp2(float x){ return __builtin_amdgcn_exp2f(x); }
__device__ __forceinline__ float flog2(float x){ return __builtin_amdgcn_logf(x); }

// One wave per batch. Lane l owns extended states 4l..4l+3 (lane 63 also 256).
// alpha = m * 2^e, per-lane integer scale e, exact pow2 rescale every 4 steps.
// p-values for all 32 steps of the current chunk live in registers, gathered
// from GLOBAL memory (vmcnt) one full chunk ahead so shfl (lgkmcnt) waits
// never drain them (DS/VM counters retire in order per-counter).
__global__ __launch_bounds__(64,1)
void ctc_fwd_kernel(const int* __restrict__ y_true,
                    const float* __restrict__ y_pred,
                    const int* __restrict__ input_len,
                    const int* __restrict__ label_len,
                    float* __restrict__ out)
{
    __shared__ float lg_alpha[NS + 3];

    const int b    = blockIdx.x;
    const int lane = threadIdx.x;
    const float* __restrict__ base = y_pred + (size_t)b * NT * NC;

    int Tn = input_len[b];
    Tn = Tn < 0 ? 0 : (Tn > NT ? NT : Tn);

    const int* __restrict__ yrow = y_true + b * NL;
    const int y0v = yrow[2 * lane]     & (NC - 1);   // label for state 4l+1
    const int y1v = yrow[2 * lane + 1] & (NC - 1);   // label for state 4l+3
    const int yp  = __shfl_up(y1v, 1, 64);           // y[2l-1]
    const bool skip1 = (lane > 0) && (y0v != yp);
    const bool skip3 = (y1v != y0v);
    const bool isl0  = (lane == 0);
    const bool isl63 = (lane == 63);

    float m0 = isl0 ? 1.f : 0.f, m1 = 0.f, m2 = 0.f, m3 = 0.f, m4 = 0.f;
    float e   = 0.f;              // per-lane log2 scale (integer-valued, exact)
    float f0  = isl0 ? 0.f : 1.f; // neighbor->self scale factor (per group)
    float fs1 = skip1 ? f0 : 0.f;
    float shm3 = 0.f;             // neighbor's m3 (prev step), neighbor scale

    // p registers for the current chunk: [group][row-in-group]
    float pB[8][4], pA[8][4], pC[8][4];   // blank, y0v, y1v

    auto gather1 = [&](int chunk, int g) {             // 12 loads, group g
        const float* rp = base + ((size_t)chunk * CHUNK + g * 4) * NC;
        #pragma unroll
        for (int r = 0; r < 4; ++r) {
            pB[g][r] = rp[r * NC + (NC - 1)];
            pA[g][r] = rp[r * NC + y0v];
            pC[g][r] = rp[r * NC + y1v];
        }
    };

    auto step1 = [&](float Pb, float Pa, float Pc) {
        Pb += EPSF; Pa += EPSF; Pc += EPSF;
        float t3  = skip3 ? m1 : 0.f;
        float n3  = Pc * ((m3 + m2) + t3);
        float n2  = Pb * (m2 + m1);
        float n4  = Pb * (m4 + m3);
        float pm1 = shm3 * f0;                 // alpha[4l-1] in own scale
        float t1  = shm3 * fs1;
        float n0  = Pb * (m0 + pm1);
        float n1  = Pa * ((m1 + m0) + t1);
        m0 = n0; m1 = n1; m2 = n2; m3 = n3; m4 = n4;
    };

    auto boundary = [&](bool early) {
        float mx = fmaxf(fmaxf(m0, m1), fmaxf(m2, m3));
        if (isl63) mx = fmaxf(mx, m4);
        const uint32_t bx = __float_as_uint(mx);
        const uint32_t eb = bx >> 23;
        const float inv = __uint_as_float((254u - eb) << 23);  // exact 2^-ef
        const float ef  = (float)((int)eb - 127);
        const bool dead = (mx == 0.f);
        if (early) {
            // two-pass adoption: dead lanes (no mass yet) take neighbor's
            // scale so the first incoming mass isn't mis-scaled. Two passes
            // cover the deepest dead lane mass can reach within one group.
            float e1 = dead ? e : (e + ef);
            float s1 = __shfl_up(e1, 1, 64);
            float e2 = (dead && !isl0) ? s1 : e1;
            float s2 = __shfl_up(e2, 1, 64);
            e = (dead && !isl0) ? s2 : e2;
            float d = fminf(fmaxf(s2 - e, -126.f), 126.f);
            f0 = isl0 ? 0.f : fexp2(d);
        } else {
            e = dead ? e : (e + ef);
            float s1 = __shfl_up(e, 1, 64);
            float d = fminf(fmaxf(s1 - e, -126.f), 126.f);
            f0 = isl0 ? 0.f : fexp2(d);
        }
        fs1 = skip1 ? f0 : 0.f;
        m0 *= inv; m1 *= inv; m2 *= inv; m3 *= inv; m4 *= inv;
        shm3 = __shfl_up(m3, 1, 64);           // post-rescale, matches new f0
    };

    auto step4 = [&](int g) {
        #pragma unroll
        for (int r = 0; r < 4; ++r) {
            step1(pB[g][r], pA[g][r], pC[g][r]);
            if (r < 3) shm3 = __shfl_up(m3, 1, 64);
        }
    };

    auto chunkbody = [&](int k, bool early) {
        const bool more = (k + 1) < (NT / CHUNK);
        #pragma unroll
        for (int g = 0; g < 8; ++g) {
            step4(g);                 // consume group g (regs now free)
            boundary(early);
            if (more) gather1(k + 1, g);   // refill for next chunk (WAR-safe)
        }
    };

    // prologue: gather chunk 0
    #pragma unroll
    for (int g = 0; g < 8; ++g) gather1(0, g);

    const int nfull = Tn >> 5;
    const int rem32 = Tn & 31;

    int k = 0;
    const int e8 = nfull < 8 ? nfull : 8;
    for (; k < e8;    ++k) chunkbody(k, true);    // t < 256: dead lanes possible
    for (; k < nfull; ++k) chunkbody(k, false);   // all lanes alive

    if (rem32) {                                   // tail chunk (index nfull)
        const bool early = (nfull < 8);
        const int tg = rem32 >> 2, rem = rem32 & 3;
        #pragma unroll
        for (int g = 0; g < 8; ++g) {
            if (g < tg) { step4(g); boundary(early); }
        }
        #pragma unroll
        for (int g = 0; g < 8; ++g) {
            if (g == tg) {
                #pragma unroll
                for (int r = 0; r < 3; ++r) {
                    if (r < rem) {
                        step1(pB[g][r], pA[g][r], pC[g][r]);
                        shm3 = __shfl_up(m3, 1, 64);
                    }
                }
            }
        }
    }

    // ---- epilogue ----
    lg_alpha[4 * lane + 0] = (m0 > 0.f) ? (e + flog2(m0)) : NEGL2;
    lg_alpha[4 * lane + 1] = (m1 > 0.f) ? (e + flog2(m1)) : NEGL2;
    lg_alpha[4 * lane + 2] = (m2 > 0.f) ? (e + flog2(m2)) : NEGL2;
    lg_alpha[4 * lane + 3] = (m3 > 0.f) ? (e + flog2(m3)) : NEGL2;
    if (isl63) lg_alpha[256] = (m4 > 0.f) ? (e + flog2(m4)) : NEGL2;
    __syncthreads();

    if (lane == 0) {
        int lab = label_len[b];
        lab = lab < 0 ? 0 : (lab > NL ? NL : lab);
        const int i_last = 2 * lab;
        const int i_prev = i_last > 0 ? i_last - 1 : 0;
        float A  = lg_alpha[i_last];
        float Bv = lg_alpha[i_prev];
        float mx = fmaxf(A, Bv);
        float r;
        if (mx < -1.0e29f) {
            r = mx;
        } else {
            float s = fexp2(A - mx) + fexp2(Bv - mx);
            r = mx + flog2(s);
        }
        out[b] = -r * LN2F;
    }
}

extern "C" void kernel_launch(void* const* d_in, const int* in_sizes, int n_in,
                              void* d_out, int out_size, void* d_ws, size_t ws_size,
                              hipStream_t stream) {
    const int*   y_true    = (const int*)d_in[0];
    const float* y_pred    = (const float*)d_in[1];
    const int*   input_len = (const int*)d_in[2];
    const int*   label_len = (const int*)d_in[3];
    float* outp = (float*)d_out;
    ctc_fwd_kernel<<<dim3(NB), dim3(64), 0, stream>>>(y_true, y_pred, input_len, label_len, outp);
}

// Round 3
// 221.626 us; speedup vs baseline: 1.0701x; 1.0701x over previous
//
#include <hip/hip_runtime.h>
#include <cstdint>

#define NB 128
#define NT 1024
#define NC 128
#define NL 128
#define NS 257
#define EPSF 1e-7f
#define CHUNK 32
#define LN2F 0.69314718055994530942f
#define NEGL2 -1.442695e30f   // *ln2 ~= -1e30 (reference NEG)

__device__ __forceinline__ float fexp2(float x){ return __builtin_amdgcn_exp2f(x); }
__device__ __forceinline__ float flog2(float x){ return __builtin_amdgcn_logf(x); }

// Wave-wide shift-up-by-1 in the VALU pipe (no LDS round-trip, no lgkmcnt):
// v_mov_b32_dpp wave_shr:1 (ctrl 0x138). Lane 0 receives 0 (bound_ctrl=1).
// NOTE: differs from __shfl_up at lane 0 (0, not own value) — all call sites
// below are lane-0-safe (multiplied by forced-zero factor or guarded).
__device__ __forceinline__ float shup1(float x) {
    int r = __builtin_amdgcn_update_dpp(0, __float_as_int(x), 0x138, 0xf, 0xf, true);
    return __int_as_float(r);
}
__device__ __forceinline__ int shup1i(int x) {
    return __builtin_amdgcn_update_dpp(0, x, 0x138, 0xf, 0xf, true);
}

// One wave per batch. Lane l owns extended states 4l..4l+3 (lane 63 also 256).
// alpha = m * 2^e, per-lane integer scale e, exact pow2 rescale every 4 steps.
// p-values for the whole chunk live in registers, gathered from GLOBAL memory
// one full chunk ahead (vmcnt-only, off the serial chain).
__global__ __launch_bounds__(64,1)
void ctc_fwd_kernel(const int* __restrict__ y_true,
                    const float* __restrict__ y_pred,
                    const int* __restrict__ input_len,
                    const int* __restrict__ label_len,
                    float* __restrict__ out)
{
    __shared__ float lg_alpha[NS + 3];

    const int b    = blockIdx.x;
    const int lane = threadIdx.x;
    const float* __restrict__ base = y_pred + (size_t)b * NT * NC;

    int Tn = input_len[b];
    Tn = Tn < 0 ? 0 : (Tn > NT ? NT : Tn);

    const int* __restrict__ yrow = y_true + b * NL;
    const int y0v = yrow[2 * lane]     & (NC - 1);   // label for state 4l+1
    const int y1v = yrow[2 * lane + 1] & (NC - 1);   // label for state 4l+3
    const int yp  = shup1i(y1v);                     // y[2l-1] (lane0: unused)
    const bool skip1 = (lane > 0) && (y0v != yp);
    const bool skip3 = (y1v != y0v);
    const bool isl0  = (lane == 0);
    const bool isl63 = (lane == 63);

    float m0 = isl0 ? 1.f : 0.f, m1 = 0.f, m2 = 0.f, m3 = 0.f, m4 = 0.f;
    float e   = 0.f;              // per-lane log2 scale (integer-valued, exact)
    float f0  = isl0 ? 0.f : 1.f; // neighbor->self scale factor (per group)
    float fs1 = skip1 ? f0 : 0.f;
    float shm3 = 0.f;             // neighbor's m3 (prev step), neighbor scale

    // p registers for the current chunk: [group][row-in-group]
    float pB[8][4], pA[8][4], pC[8][4];   // blank, y0v, y1v

    auto gather1 = [&](int chunk, int g) {             // 12 loads, group g
        const float* rp = base + ((size_t)chunk * CHUNK + g * 4) * NC;
        #pragma unroll
        for (int r = 0; r < 4; ++r) {
            pB[g][r] = rp[r * NC + (NC - 1)];
            pA[g][r] = rp[r * NC + y0v];
            pC[g][r] = rp[r * NC + y1v];
        }
    };

    auto step1 = [&](float Pb, float Pa, float Pc) {
        Pb += EPSF; Pa += EPSF; Pc += EPSF;
        float t3  = skip3 ? m1 : 0.f;
        float n3  = Pc * ((m3 + m2) + t3);
        float n2  = Pb * (m2 + m1);
        float n4  = Pb * (m4 + m3);
        float pm1 = shm3 * f0;                 // alpha[4l-1] in own scale
        float t1  = shm3 * fs1;
        float n0  = Pb * (m0 + pm1);
        float n1  = Pa * ((m1 + m0) + t1);
        m0 = n0; m1 = n1; m2 = n2; m3 = n3; m4 = n4;
    };

    auto boundary = [&](bool early) {
        float mx = fmaxf(fmaxf(m0, m1), fmaxf(m2, m3));
        if (isl63) mx = fmaxf(mx, m4);
        const uint32_t bx = __float_as_uint(mx);
        const uint32_t eb = bx >> 23;
        const float inv = __uint_as_float((254u - eb) << 23);  // exact 2^-ef
        const float ef  = (float)((int)eb - 127);
        const bool dead = (mx == 0.f);
        if (early) {
            // two-pass adoption: dead lanes (no mass yet) take neighbor's
            // scale so the first incoming mass isn't mis-scaled.
            float e1 = dead ? e : (e + ef);
            float s1 = shup1(e1);
            float e2 = (dead && !isl0) ? s1 : e1;
            float s2 = shup1(e2);
            e = (dead && !isl0) ? s2 : e2;
            float d = fminf(fmaxf(s2 - e, -126.f), 126.f);
            f0 = isl0 ? 0.f : fexp2(d);
        } else {
            e = dead ? e : (e + ef);
            float s1 = shup1(e);
            float d = fminf(fmaxf(s1 - e, -126.f), 126.f);
            f0 = isl0 ? 0.f : fexp2(d);
        }
        fs1 = skip1 ? f0 : 0.f;
        m0 *= inv; m1 *= inv; m2 *= inv; m3 *= inv; m4 *= inv;
        shm3 = shup1(m3);                      // post-rescale, matches new f0
    };

    auto step4 = [&](int g) {
        #pragma unroll
        for (int r = 0; r < 4; ++r) {
            step1(pB[g][r], pA[g][r], pC[g][r]);
            if (r < 3) shm3 = shup1(m3);
        }
    };

    auto chunkbody = [&](int k, bool early) {
        const bool more = (k + 1) < (NT / CHUNK);
        #pragma unroll
        for (int g = 0; g < 8; ++g) {
            step4(g);                 // consume group g (regs now free)
            boundary(early);
            if (more) gather1(k + 1, g);   // refill for next chunk (WAR-safe)
        }
    };

    // prologue: gather chunk 0
    #pragma unroll
    for (int g = 0; g < 8; ++g) gather1(0, g);

    const int nfull = Tn >> 5;
    const int rem32 = Tn & 31;

    int k = 0;
    const int e8 = nfull < 8 ? nfull : 8;
    for (; k < e8;    ++k) chunkbody(k, true);    // t < 256: dead lanes possible
    for (; k < nfull; ++k) chunkbody(k, false);   // all lanes alive

    if (rem32) {                                   // tail chunk (index nfull)
        const bool early = (nfull < 8);
        const int tg = rem32 >> 2, rem = rem32 & 3;
        #pragma unroll
        for (int g = 0; g < 8; ++g) {
            if (g < tg) { step4(g); boundary(early); }
        }
        #pragma unroll
        for (int g = 0; g < 8; ++g) {
            if (g == tg) {
                #pragma unroll
                for (int r = 0; r < 3; ++r) {
                    if (r < rem) {
                        step1(pB[g][r], pA[g][r], pC[g][r]);
                        shm3 = shup1(m3);
                    }
                }
            }
        }
    }

    // ---- epilogue ----
    lg_alpha[4 * lane + 0] = (m0 > 0.f) ? (e + flog2(m0)) : NEGL2;
    lg_alpha[4 * lane + 1] = (m1 > 0.f) ? (e + flog2(m1)) : NEGL2;
    lg_alpha[4 * lane + 2] = (m2 > 0.f) ? (e + flog2(m2)) : NEGL2;
    lg_alpha[4 * lane + 3] = (m3 > 0.f) ? (e + flog2(m3)) : NEGL2;
    if (isl63) lg_alpha[256] = (m4 > 0.f) ? (e + flog2(m4)) : NEGL2;
    __syncthreads();

    if (lane == 0) {
        int lab = label_len[b];
        lab = lab < 0 ? 0 : (lab > NL ? NL : lab);
        const int i_last = 2 * lab;
        const int i_prev = i_last > 0 ? i_last - 1 : 0;
        float A  = lg_alpha[i_last];
        float Bv = lg_alpha[i_prev];
        float mx = fmaxf(A, Bv);
        float r;
        if (mx < -1.0e29f) {
            r = mx;
        } else {
            float s = fexp2(A - mx) + fexp2(Bv - mx);
            r = mx + flog2(s);
        }
        out[b] = -r * LN2F;
    }
}

extern "C" void kernel_launch(void* const* d_in, const int* in_sizes, int n_in,
                              void* d_out, int out_size, void* d_ws, size_t ws_size,
                              hipStream_t stream) {
    const int*   y_true    = (const int*)d_in[0];
    const float* y_pred    = (const float*)d_in[1];
    const int*   input_len = (const int*)d_in[2];
    const int*   label_len = (const int*)d_in[3];
    float* outp = (float*)d_out;
    ctc_fwd_kernel<<<dim3(NB), dim3(64), 0, stream>>>(y_true, y_pred, input_len, label_len, outp);
}